// Round 23
// baseline (50.160 us; speedup 1.0000x reference)
//
#include <hip/hip_runtime.h>
#include <hip/hip_bf16.h>

// EquivariantConvolution via bf16 MFMA — R23: R22 text (passed, 43.4us) scaled
// BM 256->512, TPB 512->1024 (16 waves), grid 512, 2 blocks/CU. Dose-response:
// BM=128 -> 59.6us, BM=256 -> 43.4us (staging + barrier-phases amortize over BM).
// Staging re-derived for 1024 threads (a = i*16 + (tt>>3), g = (tt>>1)&3,
// i0 = (tt&1)*4 — same carry-free derivation shape as the passing 256/512 forms).
// All other formulas are BM-parameter changes; structure byte-identical to R22.
// GEMM view: C[e,a] = sum_{j,b} (h[e,j]*tmp[e,b]) * w2[j, a*32+b], K=1056 incl bias, N=32.

#define TPB 1024
#define BM  512

typedef __attribute__((ext_vector_type(8))) short bf16x8;
typedef __attribute__((ext_vector_type(2))) float f32x2;
typedef __attribute__((ext_vector_type(4))) float f32x4;
typedef __attribute__((ext_vector_type(4))) unsigned int u32x4;

__device__ __forceinline__ ushort f2bf(float x) {
    __hip_bfloat16 b = __float2bfloat16(x);
    return __builtin_bit_cast(ushort, b);
}
__device__ __forceinline__ float bf2f(ushort u) {
    unsigned int v = ((unsigned int)u) << 16;
    return __builtin_bit_cast(float, v);
}
// pack trunc-bf16(m0), trunc-bf16(m1) into one u32 (m0 -> low16, m1 -> high16)
__device__ __forceinline__ unsigned int pack_trunc(float m0, float m1) {
    return __builtin_amdgcn_perm(__builtin_bit_cast(unsigned int, m1),
                                 __builtin_bit_cast(unsigned int, m0),
                                 0x07060302u);
}

__global__ __launch_bounds__(TPB, 2) void equiv_conv_mfma(
    const float* __restrict__ basis1,
    const float* __restrict__ basis2,
    const float* __restrict__ ef,
    const float* __restrict__ f,
    const int*   __restrict__ src_idx,
    const float* __restrict__ w1,
    const float* __restrict__ b1,
    const float* __restrict__ w2,
    const float* __restrict__ b2,
    float* __restrict__ out)
{
    // LDS: hT 32KB + shared region 32KB (tmpT 32KB, then WL in first 16KB) = 64 KB.
    __shared__ ushort hT[32 * BM];        // [j][edge]  bf16 bits
    __shared__ ushort region[16384];      // tmpT [g][edge][8]; later WL [jr][g][a][i]

    ushort* tmpT = region;
    ushort* WL   = region;

    const int tid  = threadIdx.x;
    const int base = blockIdx.x * BM;

    const int jr2 = tid >> 7;     // row-in-chunk this thread stages (0..7)
    const int tt2 = tid & 127;

    // ---- issue chunk-0 w2 loads early (land under prologue compute) ----
    // thread covers row jr2, cols tt2*4 + i*512 + (0..3), i = 0..1
    f32x4 stg[2];
    {
        const float* p = w2 + jr2 * 1024 + tt2 * 4;
        #pragma unroll
        for (int i = 0; i < 2; ++i)
            stg[i] = *reinterpret_cast<const f32x4*>(p + i * 512);
    }

    // write staged regs (bf16, trunc) into WL; col = tt2*4 + i*512 + l:
    //   a = i*16 + (tt2>>3), b = (tt2&7)*4 + l -> g = (tt2>>1)&3, i0 = (tt2&1)*4.
    auto write_stage = [&]() {
        const int g   = (tt2 >> 1) & 3;
        const int i0v = (tt2 & 1) * 4;
        #pragma unroll
        for (int i = 0; i < 2; ++i) {
            const int a = i * 16 + (tt2 >> 3);
            *reinterpret_cast<uint2*>(&WL[jr2 * 1024 + g * 256 + a * 8 + i0v]) =
                make_uint2(pack_trunc(stg[i][0], stg[i][1]),
                           pack_trunc(stg[i][2], stg[i][3]));
        }
    };

    // ---- prologue (edges are owned by threads 0..511) ----
    if (tid < BM) {
        const int e = base + tid;
        // h = relu(ef@w1 + b1) -> hT (bf16)
        {
            float efr[16];
            const f32x4* p4 = reinterpret_cast<const f32x4*>(ef + e * 16);
            #pragma unroll
            for (int i = 0; i < 4; ++i) {
                f32x4 v = p4[i];
                efr[i*4+0] = v[0]; efr[i*4+1] = v[1]; efr[i*4+2] = v[2]; efr[i*4+3] = v[3];
            }
            #pragma unroll
            for (int j = 0; j < 32; ++j) {
                float hv = b1[j];
                #pragma unroll
                for (int i = 0; i < 16; ++i)
                    hv = fmaf(efr[i], w1[i * 32 + j], hv);
                hT[j * BM + tid] = f2bf(fmaxf(hv, 0.f));
            }
        }
        // tmp[m*4+k] = sum_d f_src[m][d]*basis1[d][k] -> tmpT (bf16)
        {
            float fr[32];
            const int s = src_idx[e];
            const f32x4* p4 = reinterpret_cast<const f32x4*>(f + s * 32);
            #pragma unroll
            for (int i = 0; i < 8; ++i) {
                f32x4 v = p4[i];
                fr[i*4+0] = v[0]; fr[i*4+1] = v[1]; fr[i*4+2] = v[2]; fr[i*4+3] = v[3];
            }
            float bs1[16];
            const f32x4* q4 = reinterpret_cast<const f32x4*>(basis1 + e * 16);
            #pragma unroll
            for (int i = 0; i < 4; ++i) {
                f32x4 v = q4[i];
                bs1[i*4+0] = v[0]; bs1[i*4+1] = v[1]; bs1[i*4+2] = v[2]; bs1[i*4+3] = v[3];
            }
            float tmp[32];
            #pragma unroll
            for (int m = 0; m < 8; ++m) {
                #pragma unroll
                for (int k = 0; k < 4; ++k) {
                    float v = 0.f;
                    #pragma unroll
                    for (int d = 0; d < 4; ++d)
                        v = fmaf(fr[m*4+d], bs1[d*4+k], v);
                    tmp[m*4+k] = v;
                }
            }
            #pragma unroll
            for (int g = 0; g < 4; ++g) {
                uint4 pk;
                pk.x = (unsigned int)f2bf(tmp[g*8+0]) | ((unsigned int)f2bf(tmp[g*8+1]) << 16);
                pk.y = (unsigned int)f2bf(tmp[g*8+2]) | ((unsigned int)f2bf(tmp[g*8+3]) << 16);
                pk.z = (unsigned int)f2bf(tmp[g*8+4]) | ((unsigned int)f2bf(tmp[g*8+5]) << 16);
                pk.w = (unsigned int)f2bf(tmp[g*8+6]) | ((unsigned int)f2bf(tmp[g*8+7]) << 16);
                *reinterpret_cast<uint4*>(&tmpT[(g * BM + tid) * 8]) = pk;
            }
        }
    }

    __syncthreads();                       // tmpT/hT visible to all 16 waves

    // ---- per-wave tile setup: read tmpf BEFORE region is reused as WL ----
    const int lane = tid & 63;
    const int wid  = tid >> 6;             // 0..15, owns edges wid*32 .. wid*32+31
    const int l15  = lane & 15;
    const int lg   = lane >> 4;            // K-group (b = lg*8 + i)

    f32x2 tmp2[2][4];                      // per-tile tmp[b] as f32 pairs, K-loop invariant
    #pragma unroll
    for (int q = 0; q < 2; ++q) {
        const int edge = wid * 32 + q * 16 + l15;
        bf16x8 tv = *reinterpret_cast<const bf16x8*>(&tmpT[(lg * BM + edge) * 8]);
        #pragma unroll
        for (int i = 0; i < 4; ++i) {
            tmp2[q][i][0] = bf2f((ushort)tv[2*i]);
            tmp2[q][i][1] = bf2f((ushort)tv[2*i+1]);
        }
    }

    __syncthreads();                       // WAR: all waves done reading tmpT region
    write_stage();                         // chunk 0 -> WL (same region)
    __syncthreads();                       // WL ready

    f32x4 acc[2][2];
    #pragma unroll
    for (int q = 0; q < 2; ++q) {
        #pragma unroll
        for (int t = 0; t < 2; ++t) {
            acc[q][t][0] = 0.f; acc[q][t][1] = 0.f; acc[q][t][2] = 0.f; acc[q][t][3] = 0.f;
        }
    }

    const ushort* hrow = &hT[wid * 32 + l15];   // + q*16 + kk*BM

    // ---- K-loop: 4 chunks x 8 rows, single-buffered WL ----
    #pragma unroll 1
    for (int c = 0; c < 4; ++c) {
        // issue next chunk's global loads (write to LDS after compute + barrier)
        if (c < 3) {
            const float* p = w2 + ((c + 1) * 8 + jr2) * 1024 + tt2 * 4;
            #pragma unroll
            for (int i = 0; i < 2; ++i)
                stg[i] = *reinterpret_cast<const f32x4*>(p + i * 512);
        } else if (tid < 128) {            // bias2 row (jr2==0, tt2==tid)
            const float* p = b2 + tt2 * 4;
            #pragma unroll
            for (int i = 0; i < 2; ++i)
                stg[i] = *reinterpret_cast<const f32x4*>(p + i * 512);
        }

        // ---- preload this chunk's 16 h-values (static indexing -> registers) ----
        ushort hreg[8][2];
        #pragma unroll
        for (int j8 = 0; j8 < 8; ++j8) {
            #pragma unroll
            for (int q = 0; q < 2; ++q)
                hreg[j8][q] = hrow[(c * 8 + j8) * BM + q * 16];
        }

        const ushort* Wb = WL;
        #pragma unroll
        for (int j8 = 0; j8 < 8; ++j8) {
            bf16x8 bf0 = *reinterpret_cast<const bf16x8*>(&Wb[j8 * 1024 + lg * 256 + l15 * 8]);
            bf16x8 bf1 = *reinterpret_cast<const bf16x8*>(&Wb[j8 * 1024 + lg * 256 + (16 + l15) * 8]);
            #pragma unroll
            for (int q = 0; q < 2; ++q) {
                const float hv = bf2f(hreg[j8][q]);
                const f32x2 hv2 = (f32x2){hv, hv};
                u32x4 w;
                #pragma unroll
                for (int i = 0; i < 4; ++i) {
                    f32x2 m = hv2 * tmp2[q][i];            // v_pk_mul_f32
                    w[i] = pack_trunc(m[0], m[1]);
                }
                const bf16x8 af = __builtin_bit_cast(bf16x8, w);
                acc[q][0] = __builtin_amdgcn_mfma_f32_16x16x32_bf16(af, bf0, acc[q][0], 0, 0, 0);
                acc[q][1] = __builtin_amdgcn_mfma_f32_16x16x32_bf16(af, bf1, acc[q][1], 0, 0, 0);
            }
        }

        __syncthreads();                   // everyone done reading WL
        if (c < 3) write_stage();
        else if (tid < 128) write_stage(); // bias row into row 0
        __syncthreads();                   // WL ready for next chunk / bias step
    }

    // ---- bias2 K-step (implicit h == 1, A = trunc(tmp2) == original bf16 bits) ----
    {
        bf16x8 bb0 = *reinterpret_cast<const bf16x8*>(&WL[lg * 256 + l15 * 8]);
        bf16x8 bb1 = *reinterpret_cast<const bf16x8*>(&WL[lg * 256 + (16 + l15) * 8]);
        #pragma unroll
        for (int q = 0; q < 2; ++q) {
            u32x4 w;
            #pragma unroll
            for (int i = 0; i < 4; ++i)
                w[i] = pack_trunc(tmp2[q][i][0], tmp2[q][i][1]);   // exact (values are bf16)
            const bf16x8 af = __builtin_bit_cast(bf16x8, w);
            acc[q][0] = __builtin_amdgcn_mfma_f32_16x16x32_bf16(af, bb0, acc[q][0], 0, 0, 0);
            acc[q][1] = __builtin_amdgcn_mfma_f32_16x16x32_bf16(af, bb1, acc[q][1], 0, 0, 0);
        }
    }

    // ---- epilogue: 4x4 quad transpose, then lane-local basis2 contraction ----
    // C layout (verified): lane holds col a = l15 + 16t (k2 = lane&3), rows
    // edge = q*16 + lg*4 + r in regs. Quad transpose (lane-pos p <-> reg idx):
    // after it, lane p holds all four k2 values of edge q*16 + lg*4 + p.
    const int m2l = (lane >> 2) & 3;
    const int p0  = lane & 1;
    const int p1  = (lane >> 1) & 1;
    #pragma unroll
    for (int q = 0; q < 2; ++q) {
        const int egp = base + wid * 32 + q * 16 + lg * 4 + (lane & 3);
        const f32x4* bp = reinterpret_cast<const f32x4*>(basis2 + egp * 16);
        f32x4 bsr0 = bp[0], bsr1 = bp[1], bsr2 = bp[2], bsr3 = bp[3];
        #pragma unroll
        for (int t = 0; t < 2; ++t) {
            float v0 = acc[q][t][0], v1 = acc[q][t][1];
            float v2 = acc[q][t][2], v3 = acc[q][t][3];
            // step 1 (xor 1): even.v1 <-> odd.v0, even.v3 <-> odd.v2
            float s0 = p0 ? v0 : v1;
            float r0 = __shfl_xor(s0, 1);
            if (p0) v0 = r0; else v1 = r0;
            float s1 = p0 ? v2 : v3;
            float r1 = __shfl_xor(s1, 1);
            if (p0) v2 = r1; else v3 = r1;
            // step 2 (xor 2): low.v2 <-> high.v0, low.v3 <-> high.v1
            float u0 = p1 ? v0 : v2;
            float w0 = __shfl_xor(u0, 2);
            if (p1) v0 = w0; else v2 = w0;
            float u1 = p1 ? v1 : v3;
            float w1 = __shfl_xor(u1, 2);
            if (p1) v1 = w1; else v3 = w1;
            // v[s] = C[edge egp][m2 = t*4+m2l, k2 = s] -> lane-local contraction
            f32x4 o = v0 * bsr0;
            o += v1 * bsr1;
            o += v2 * bsr2;
            o += v3 * bsr3;
            *reinterpret_cast<f32x4*>(out + egp * 32 + (t * 4 + m2l) * 4) = o;
        }
    }
}

extern "C" void kernel_launch(void* const* d_in, const int* in_sizes, int n_in,
                              void* d_out, int out_size, void* d_ws, size_t ws_size,
                              hipStream_t stream) {
    const float* basis1 = (const float*)d_in[0];
    const float* basis2 = (const float*)d_in[1];
    const float* ef     = (const float*)d_in[2];
    const float* f      = (const float*)d_in[3];
    const int*   src    = (const int*)  d_in[4];
    const float* w1     = (const float*)d_in[5];
    const float* b1     = (const float*)d_in[6];
    const float* w2     = (const float*)d_in[7];
    const float* b2     = (const float*)d_in[8];
    float* out = (float*)d_out;

    const int E = in_sizes[4];            // 262144
    const int nblocks = E / BM;           // 512

    equiv_conv_mfma<<<nblocks, TPB, 0, stream>>>(
        basis1, basis2, ef, f, src, w1, b1, w2, b2, out);
}

// Round 24
// 43.362 us; speedup vs baseline: 1.1568x; 1.1568x over previous
//
#include <hip/hip_runtime.h>
#include <hip/hip_bf16.h>

// EquivariantConvolution via bf16 MFMA — R24: consolidation, exact R22 text
// (best passing, 43.4us, absmax 2.0). BM dose-response measured: 128->59.6,
// 256->43.4 (this), 512->50.2 — BM=256/TPB=512 is the optimum.
// Structure: 8-wave block, 256 edges; hT/tmpT LDS-staged bf16; WL single-buffer
// w2 staging (pack_trunc); rank-1 A-frag built per kk (v_pk_mul_f32 + v_perm);
// mfma_f32_16x16x32_bf16; quad-transpose epilogue with lane-local basis2
// contraction and float4 stores.
// GEMM view: C[e,a] = sum_{j,b} (h[e,j]*tmp[e,b]) * w2[j, a*32+b], K=1056 incl bias, N=32.

#define TPB 512
#define BM  256

typedef __attribute__((ext_vector_type(8))) short bf16x8;
typedef __attribute__((ext_vector_type(2))) float f32x2;
typedef __attribute__((ext_vector_type(4))) float f32x4;
typedef __attribute__((ext_vector_type(4))) unsigned int u32x4;

__device__ __forceinline__ ushort f2bf(float x) {
    __hip_bfloat16 b = __float2bfloat16(x);
    return __builtin_bit_cast(ushort, b);
}
__device__ __forceinline__ float bf2f(ushort u) {
    unsigned int v = ((unsigned int)u) << 16;
    return __builtin_bit_cast(float, v);
}
// pack trunc-bf16(m0), trunc-bf16(m1) into one u32 (m0 -> low16, m1 -> high16)
__device__ __forceinline__ unsigned int pack_trunc(float m0, float m1) {
    return __builtin_amdgcn_perm(__builtin_bit_cast(unsigned int, m1),
                                 __builtin_bit_cast(unsigned int, m0),
                                 0x07060302u);
}

__global__ __launch_bounds__(TPB, 6) void equiv_conv_mfma(
    const float* __restrict__ basis1,
    const float* __restrict__ basis2,
    const float* __restrict__ ef,
    const float* __restrict__ f,
    const int*   __restrict__ src_idx,
    const float* __restrict__ w1,
    const float* __restrict__ b1,
    const float* __restrict__ w2,
    const float* __restrict__ b2,
    float* __restrict__ out)
{
    // LDS: hT 16KB + shared region 16KB (tmpT then WL) = 32 KB.
    __shared__ ushort hT[32 * BM];        // [j][edge]  bf16 bits
    __shared__ ushort region[8192];       // first tmpT [g][edge][8], then WL [jr][g][a][i]

    ushort* tmpT = region;
    ushort* WL   = region;

    const int tid  = threadIdx.x;
    const int base = blockIdx.x * BM;

    const int jr2 = tid >> 6;     // row-in-chunk this thread stages (0..7)
    const int tt2 = tid & 63;

    // ---- issue chunk-0 w2 loads early (land under prologue compute) ----
    f32x4 stg[4];
    {
        const float* p = w2 + jr2 * 1024 + tt2 * 4;
        #pragma unroll
        for (int i = 0; i < 4; ++i)
            stg[i] = *reinterpret_cast<const f32x4*>(p + i * 256);
    }

    // write staged regs (bf16, trunc) into WL; col = tt2*4 + i*256 + l:
    //   a = i*8 + (tt2>>3), b = (tt2&7)*4 + l -> g = (tt2>>1)&3, i0 = (tt2&1)*4.
    auto write_stage = [&]() {
        const int g   = (tt2 >> 1) & 3;
        const int i0v = (tt2 & 1) * 4;
        #pragma unroll
        for (int i = 0; i < 4; ++i) {
            const int a = i * 8 + (tt2 >> 3);
            *reinterpret_cast<uint2*>(&WL[jr2 * 1024 + g * 256 + a * 8 + i0v]) =
                make_uint2(pack_trunc(stg[i][0], stg[i][1]),
                           pack_trunc(stg[i][2], stg[i][3]));
        }
    };

    // ---- prologue (edges are owned by threads 0..255) ----
    if (tid < BM) {
        const int e = base + tid;
        // h = relu(ef@w1 + b1) -> hT (bf16)
        {
            float efr[16];
            const f32x4* p4 = reinterpret_cast<const f32x4*>(ef + e * 16);
            #pragma unroll
            for (int i = 0; i < 4; ++i) {
                f32x4 v = p4[i];
                efr[i*4+0] = v[0]; efr[i*4+1] = v[1]; efr[i*4+2] = v[2]; efr[i*4+3] = v[3];
            }
            #pragma unroll
            for (int j = 0; j < 32; ++j) {
                float hv = b1[j];
                #pragma unroll
                for (int i = 0; i < 16; ++i)
                    hv = fmaf(efr[i], w1[i * 32 + j], hv);
                hT[j * BM + tid] = f2bf(fmaxf(hv, 0.f));
            }
        }
        // tmp[m*4+k] = sum_d f_src[m][d]*basis1[d][k] -> tmpT (bf16)
        {
            float fr[32];
            const int s = src_idx[e];
            const f32x4* p4 = reinterpret_cast<const f32x4*>(f + s * 32);
            #pragma unroll
            for (int i = 0; i < 8; ++i) {
                f32x4 v = p4[i];
                fr[i*4+0] = v[0]; fr[i*4+1] = v[1]; fr[i*4+2] = v[2]; fr[i*4+3] = v[3];
            }
            float bs1[16];
            const f32x4* q4 = reinterpret_cast<const f32x4*>(basis1 + e * 16);
            #pragma unroll
            for (int i = 0; i < 4; ++i) {
                f32x4 v = q4[i];
                bs1[i*4+0] = v[0]; bs1[i*4+1] = v[1]; bs1[i*4+2] = v[2]; bs1[i*4+3] = v[3];
            }
            float tmp[32];
            #pragma unroll
            for (int m = 0; m < 8; ++m) {
                #pragma unroll
                for (int k = 0; k < 4; ++k) {
                    float v = 0.f;
                    #pragma unroll
                    for (int d = 0; d < 4; ++d)
                        v = fmaf(fr[m*4+d], bs1[d*4+k], v);
                    tmp[m*4+k] = v;
                }
            }
            #pragma unroll
            for (int g = 0; g < 4; ++g) {
                uint4 pk;
                pk.x = (unsigned int)f2bf(tmp[g*8+0]) | ((unsigned int)f2bf(tmp[g*8+1]) << 16);
                pk.y = (unsigned int)f2bf(tmp[g*8+2]) | ((unsigned int)f2bf(tmp[g*8+3]) << 16);
                pk.z = (unsigned int)f2bf(tmp[g*8+4]) | ((unsigned int)f2bf(tmp[g*8+5]) << 16);
                pk.w = (unsigned int)f2bf(tmp[g*8+6]) | ((unsigned int)f2bf(tmp[g*8+7]) << 16);
                *reinterpret_cast<uint4*>(&tmpT[(g * BM + tid) * 8]) = pk;
            }
        }
    }

    __syncthreads();                       // tmpT/hT visible to all 8 waves

    // ---- per-wave tile setup: read tmpf BEFORE region is reused as WL ----
    const int lane = tid & 63;
    const int wid  = tid >> 6;             // 0..7, owns edges wid*32 .. wid*32+31
    const int l15  = lane & 15;
    const int lg   = lane >> 4;            // K-group (b = lg*8 + i)

    f32x2 tmp2[2][4];                      // per-tile tmp[b] as f32 pairs, K-loop invariant
    #pragma unroll
    for (int q = 0; q < 2; ++q) {
        const int edge = wid * 32 + q * 16 + l15;
        bf16x8 tv = *reinterpret_cast<const bf16x8*>(&tmpT[(lg * BM + edge) * 8]);
        #pragma unroll
        for (int i = 0; i < 4; ++i) {
            tmp2[q][i][0] = bf2f((ushort)tv[2*i]);
            tmp2[q][i][1] = bf2f((ushort)tv[2*i+1]);
        }
    }

    __syncthreads();                       // WAR: all waves done reading tmpT region
    write_stage();                         // chunk 0 -> WL (same region)
    __syncthreads();                       // WL ready

    f32x4 acc[2][2];
    #pragma unroll
    for (int q = 0; q < 2; ++q) {
        #pragma unroll
        for (int t = 0; t < 2; ++t) {
            acc[q][t][0] = 0.f; acc[q][t][1] = 0.f; acc[q][t][2] = 0.f; acc[q][t][3] = 0.f;
        }
    }

    const ushort* hrow = &hT[wid * 32 + l15];   // + q*16 + kk*BM

    // ---- K-loop: 4 chunks x 8 rows, single-buffered WL ----
    #pragma unroll 1
    for (int c = 0; c < 4; ++c) {
        // issue next chunk's global loads (write to LDS after compute + barrier)
        if (c < 3) {
            const float* p = w2 + ((c + 1) * 8 + jr2) * 1024 + tt2 * 4;
            #pragma unroll
            for (int i = 0; i < 4; ++i)
                stg[i] = *reinterpret_cast<const f32x4*>(p + i * 256);
        } else if (tid < 64) {             // bias2 row (jr2==0, tt2==tid)
            const float* p = b2 + tt2 * 4;
            #pragma unroll
            for (int i = 0; i < 4; ++i)
                stg[i] = *reinterpret_cast<const f32x4*>(p + i * 256);
        }

        // ---- preload this chunk's 16 h-values (static indexing -> registers) ----
        ushort hreg[8][2];
        #pragma unroll
        for (int j8 = 0; j8 < 8; ++j8) {
            #pragma unroll
            for (int q = 0; q < 2; ++q)
                hreg[j8][q] = hrow[(c * 8 + j8) * BM + q * 16];
        }

        const ushort* Wb = WL;
        #pragma unroll
        for (int j8 = 0; j8 < 8; ++j8) {
            bf16x8 bf0 = *reinterpret_cast<const bf16x8*>(&Wb[j8 * 1024 + lg * 256 + l15 * 8]);
            bf16x8 bf1 = *reinterpret_cast<const bf16x8*>(&Wb[j8 * 1024 + lg * 256 + (16 + l15) * 8]);
            #pragma unroll
            for (int q = 0; q < 2; ++q) {
                const float hv = bf2f(hreg[j8][q]);
                const f32x2 hv2 = (f32x2){hv, hv};
                u32x4 w;
                #pragma unroll
                for (int i = 0; i < 4; ++i) {
                    f32x2 m = hv2 * tmp2[q][i];            // v_pk_mul_f32
                    w[i] = pack_trunc(m[0], m[1]);
                }
                const bf16x8 af = __builtin_bit_cast(bf16x8, w);
                acc[q][0] = __builtin_amdgcn_mfma_f32_16x16x32_bf16(af, bf0, acc[q][0], 0, 0, 0);
                acc[q][1] = __builtin_amdgcn_mfma_f32_16x16x32_bf16(af, bf1, acc[q][1], 0, 0, 0);
            }
        }

        __syncthreads();                   // everyone done reading WL
        if (c < 3) write_stage();
        else if (tid < 64) write_stage();  // bias row into row 0
        __syncthreads();                   // WL ready for next chunk / bias step
    }

    // ---- bias2 K-step (implicit h == 1, A = trunc(tmp2) == original bf16 bits) ----
    {
        bf16x8 bb0 = *reinterpret_cast<const bf16x8*>(&WL[lg * 256 + l15 * 8]);
        bf16x8 bb1 = *reinterpret_cast<const bf16x8*>(&WL[lg * 256 + (16 + l15) * 8]);
        #pragma unroll
        for (int q = 0; q < 2; ++q) {
            u32x4 w;
            #pragma unroll
            for (int i = 0; i < 4; ++i)
                w[i] = pack_trunc(tmp2[q][i][0], tmp2[q][i][1]);   // exact (values are bf16)
            const bf16x8 af = __builtin_bit_cast(bf16x8, w);
            acc[q][0] = __builtin_amdgcn_mfma_f32_16x16x32_bf16(af, bb0, acc[q][0], 0, 0, 0);
            acc[q][1] = __builtin_amdgcn_mfma_f32_16x16x32_bf16(af, bb1, acc[q][1], 0, 0, 0);
        }
    }

    // ---- epilogue: 4x4 quad transpose, then lane-local basis2 contraction ----
    // C layout (verified): lane holds col a = l15 + 16t (k2 = lane&3), rows
    // edge = q*16 + lg*4 + r in regs. Quad transpose (lane-pos p <-> reg idx):
    // after it, lane p holds all four k2 values of edge q*16 + lg*4 + p.
    const int m2l = (lane >> 2) & 3;
    const int p0  = lane & 1;
    const int p1  = (lane >> 1) & 1;
    #pragma unroll
    for (int q = 0; q < 2; ++q) {
        const int egp = base + wid * 32 + q * 16 + lg * 4 + (lane & 3);
        const f32x4* bp = reinterpret_cast<const f32x4*>(basis2 + egp * 16);
        f32x4 bsr0 = bp[0], bsr1 = bp[1], bsr2 = bp[2], bsr3 = bp[3];
        #pragma unroll
        for (int t = 0; t < 2; ++t) {
            float v0 = acc[q][t][0], v1 = acc[q][t][1];
            float v2 = acc[q][t][2], v3 = acc[q][t][3];
            // step 1 (xor 1): even.v1 <-> odd.v0, even.v3 <-> odd.v2
            float s0 = p0 ? v0 : v1;
            float r0 = __shfl_xor(s0, 1);
            if (p0) v0 = r0; else v1 = r0;
            float s1 = p0 ? v2 : v3;
            float r1 = __shfl_xor(s1, 1);
            if (p0) v2 = r1; else v3 = r1;
            // step 2 (xor 2): low.v2 <-> high.v0, low.v3 <-> high.v1
            float u0 = p1 ? v0 : v2;
            float w0 = __shfl_xor(u0, 2);
            if (p1) v0 = w0; else v2 = w0;
            float u1 = p1 ? v1 : v3;
            float w1 = __shfl_xor(u1, 2);
            if (p1) v1 = w1; else v3 = w1;
            // v[s] = C[edge egp][m2 = t*4+m2l, k2 = s] -> lane-local contraction
            f32x4 o = v0 * bsr0;
            o += v1 * bsr1;
            o += v2 * bsr2;
            o += v3 * bsr3;
            *reinterpret_cast<f32x4*>(out + egp * 32 + (t * 4 + m2l) * 4) = o;
        }
    }
}

extern "C" void kernel_launch(void* const* d_in, const int* in_sizes, int n_in,
                              void* d_out, int out_size, void* d_ws, size_t ws_size,
                              hipStream_t stream) {
    const float* basis1 = (const float*)d_in[0];
    const float* basis2 = (const float*)d_in[1];
    const float* ef     = (const float*)d_in[2];
    const float* f      = (const float*)d_in[3];
    const int*   src    = (const int*)  d_in[4];
    const float* w1     = (const float*)d_in[5];
    const float* b1     = (const float*)d_in[6];
    const float* w2     = (const float*)d_in[7];
    const float* b2     = (const float*)d_in[8];
    float* out = (float*)d_out;

    const int E = in_sizes[4];            // 262144
    const int nblocks = E / BM;           // 1024

    equiv_conv_mfma<<<nblocks, TPB, 0, stream>>>(
        basis1, basis2, ef, f, src, w1, b1, w2, b2, out);
}